// Round 2
// baseline (408.951 us; speedup 1.0000x reference)
//
#include <hip/hip_runtime.h>
#include <hip/hip_bf16.h>

#define D_IN 32
#define D_OUT 64

// deg[i] = 1.0 (self-loop contribution to degree)
__global__ void k_init_deg(float* __restrict__ deg, int n) {
    int i = blockIdx.x * blockDim.x + threadIdx.x;
    if (i < n) deg[i] = 1.0f;
}

// xw = x @ W   (x: [N,32], W: [32,64])
__global__ void k_xw(const float* __restrict__ x, const float* __restrict__ W,
                     float* __restrict__ xw, int n) {
    __shared__ float Ws[D_IN * D_OUT];
    for (int t = threadIdx.x; t < D_IN * D_OUT; t += blockDim.x) Ws[t] = W[t];
    __syncthreads();
    int g = blockIdx.x * blockDim.x + threadIdx.x;
    if (g >= n * D_OUT) return;
    int r = g >> 6, c = g & 63;
    const float* xr = x + (size_t)r * D_IN;
    float s = 0.f;
#pragma unroll
    for (int k = 0; k < D_IN; ++k) s += xr[k] * Ws[k * D_OUT + c];
    xw[g] = s;
}

// deg[dst[e]] += 1
__global__ void k_deg(const int* __restrict__ dst, float* __restrict__ deg, int E) {
    int e = blockIdx.x * blockDim.x + threadIdx.x;
    if (e < E) atomicAdd(&deg[dst[e]], 1.0f);
}

// deg -> rsqrt(deg) in place (deg >= 1 always due to self-loops)
__global__ void k_dinv(float* __restrict__ deg, int n) {
    int i = blockIdx.x * blockDim.x + threadIdx.x;
    if (i < n) deg[i] = rsqrtf(deg[i]);
}

// agg = xw * dinv^2  (self-loop message; full overwrite, no zero-init needed)
__global__ void k_self(const float* __restrict__ xw, const float* __restrict__ dinv,
                       float* __restrict__ agg, int n) {
    int g = blockIdx.x * blockDim.x + threadIdx.x;
    if (g >= n * D_OUT) return;
    int r = g >> 6;
    float d = dinv[r];
    agg[g] = xw[g] * d * d;
}

// agg[dst] += xw[src] * dinv[src] * dinv[dst]   (64 lanes per edge)
__global__ void k_scatter(const int* __restrict__ src, const int* __restrict__ dst,
                          const float* __restrict__ xw, const float* __restrict__ dinv,
                          float* __restrict__ agg, int E) {
    int g = blockIdx.x * blockDim.x + threadIdx.x;
    int e = g >> 6, c = g & 63;
    if (e >= E) return;
    int s = src[e], d = dst[e];
    float norm = dinv[s] * dinv[d];
    atomicAdd(&agg[(size_t)d * D_OUT + c], xw[(size_t)s * D_OUT + c] * norm);
}

// h = relu(agg + b), in place
__global__ void k_relu_bias(float* __restrict__ agg, const float* __restrict__ b, int n) {
    int g = blockIdx.x * blockDim.x + threadIdx.x;
    if (g >= n * D_OUT) return;
    int c = g & 63;
    float v = agg[g] + b[c];
    agg[g] = v > 0.f ? v : 0.f;
}

// out[e] = sigmoid(<h[i], h[j]>) + 1e-15   (one wave per edge)
__global__ void k_decode(const int* __restrict__ e0, const int* __restrict__ e1,
                         const float* __restrict__ h, float* __restrict__ out, int E) {
    int g = blockIdx.x * blockDim.x + threadIdx.x;
    int e = g >> 6, c = g & 63;
    if (e >= E) return;
    int i = e0[e], j = e1[e];
    float p = h[(size_t)i * D_OUT + c] * h[(size_t)j * D_OUT + c];
#pragma unroll
    for (int off = 32; off >= 1; off >>= 1) p += __shfl_xor(p, off, 64);
    if (c == 0) {
        float sig = 1.0f / (1.0f + expf(-p)) + 1e-15f;
        out[e] = sig;
    }
}

// copy edge_index (int) into output as float32 numeric values
__global__ void k_copyidx(const int* __restrict__ ei, float* __restrict__ out, int n) {
    int g = blockIdx.x * blockDim.x + threadIdx.x;
    if (g < n) out[g] = (float)ei[g];
}

extern "C" void kernel_launch(void* const* d_in, const int* in_sizes, int n_in,
                              void* d_out, int out_size, void* d_ws, size_t ws_size,
                              hipStream_t stream) {
    const float* x = (const float*)d_in[0];
    const int*   ei = (const int*)d_in[1];
    const float* W = (const float*)d_in[2];
    const float* b = (const float*)d_in[3];

    const int N = in_sizes[0] / D_IN;
    const int E = in_sizes[1] / 2;

    float* out = (float*)d_out;  // [adj_pred (E), edge_index-as-float (2E)]

    float* ws  = (float*)d_ws;
    float* xw  = ws;                          // N*64 floats
    float* agg = ws + (size_t)N * D_OUT;      // N*64 floats
    float* deg = ws + 2 * (size_t)N * D_OUT;  // N floats (deg -> dinv in place)

    const int* srcv = ei;      // edge_index[0] : message sources
    const int* dstv = ei + E;  // edge_index[1] : aggregation targets

    const int B = 256;
    const int gN   = (N + B - 1) / B;
    const int gNF  = ((int)((size_t)N * D_OUT) + B - 1) / B;
    const int gE   = (E + B - 1) / B;
    const long long ef = (long long)E * D_OUT;
    const int gEF  = (int)((ef + B - 1) / B);
    const int g2E  = (2 * E + B - 1) / B;

    k_init_deg<<<gN,  B, 0, stream>>>(deg, N);
    k_xw      <<<gNF, B, 0, stream>>>(x, W, xw, N);
    k_deg     <<<gE,  B, 0, stream>>>(dstv, deg, E);
    k_dinv    <<<gN,  B, 0, stream>>>(deg, N);
    k_self    <<<gNF, B, 0, stream>>>(xw, deg, agg, N);
    k_scatter <<<gEF, B, 0, stream>>>(srcv, dstv, xw, deg, agg, E);
    k_relu_bias<<<gNF, B, 0, stream>>>(agg, b, N);
    k_decode  <<<gEF, B, 0, stream>>>(srcv, dstv, agg, out, E);
    k_copyidx <<<g2E, B, 0, stream>>>(ei, out + E, 2 * E);
}

// Round 3
// 320.753 us; speedup vs baseline: 1.2750x; 1.2750x over previous
//
#include <hip/hip_runtime.h>
#include <hip/hip_bf16.h>

#define D_IN 32
#define D_OUT 64
#define SCAN_T 1024

// cnt[i] = 0
__global__ void k_zero(int* __restrict__ cnt, int n) {
    int i = blockIdx.x * blockDim.x + threadIdx.x;
    if (i < n) cnt[i] = 0;
}

// xw = x @ W   (x: [N,32], W: [32,64])
__global__ void k_xw(const float* __restrict__ x, const float* __restrict__ W,
                     float* __restrict__ xw, int n) {
    __shared__ float Ws[D_IN * D_OUT];
    for (int t = threadIdx.x; t < D_IN * D_OUT; t += blockDim.x) Ws[t] = W[t];
    __syncthreads();
    int g = blockIdx.x * blockDim.x + threadIdx.x;
    if (g >= n * D_OUT) return;
    int r = g >> 6, c = g & 63;
    const float* xr = x + (size_t)r * D_IN;
    float s = 0.f;
#pragma unroll
    for (int k = 0; k < D_IN; ++k) s += xr[k] * Ws[k * D_OUT + c];
    xw[g] = s;
}

// cnt[dst[e]] += 1  (int atomics, one per edge)
__global__ void k_deg(const int* __restrict__ dst, int* __restrict__ cnt, int E) {
    int e = blockIdx.x * blockDim.x + threadIdx.x;
    if (e < E) atomicAdd(&cnt[dst[e]], 1);
}

// exclusive prefix sum of cnt[0..n) -> off[0..n], single block
__global__ void k_scan(const int* __restrict__ cnt, int* __restrict__ off, int n) {
    __shared__ int part[SCAN_T];
    int t = threadIdx.x;
    int per = (n + SCAN_T - 1) / SCAN_T;
    int s0 = t * per;
    int s1 = s0 + per; if (s1 > n) s1 = n;
    int sum = 0;
    for (int i = s0; i < s1; ++i) sum += cnt[i];
    part[t] = sum;
    __syncthreads();
    // Hillis-Steele inclusive scan over 1024 partials
    for (int d = 1; d < SCAN_T; d <<= 1) {
        int v = (t >= d) ? part[t - d] : 0;
        __syncthreads();
        part[t] += v;
        __syncthreads();
    }
    int base = part[t] - sum;  // exclusive start of this strip
    int running = base;
    for (int i = s0; i < s1; ++i) {
        off[i] = running;
        running += cnt[i];
    }
    if (t == SCAN_T - 1) off[n] = part[SCAN_T - 1];
}

// dinv[i] = rsqrt(cnt[i] + 1)   (self-loop included)
__global__ void k_dinv(const int* __restrict__ cnt, float* __restrict__ dinv, int n) {
    int i = blockIdx.x * blockDim.x + threadIdx.x;
    if (i < n) dinv[i] = rsqrtf((float)(cnt[i] + 1));
}

// bucket-fill: srcs[off[d] + slot] = src[e], consuming cnt as a down-counter
__global__ void k_fill(const int* __restrict__ src, const int* __restrict__ dst,
                       const int* __restrict__ off, int* __restrict__ cnt,
                       int* __restrict__ srcs, int E) {
    int e = blockIdx.x * blockDim.x + threadIdx.x;
    if (e >= E) return;
    int d = dst[e];
    int slot = atomicSub(&cnt[d], 1) - 1;  // unique in [0, deg)
    srcs[off[d] + slot] = src[e];
}

// one wave per node: h[d] = relu( xw[d]*dinv[d]^2 + sum_e xw[src]*dinv[src]*dinv[d] + b )
__global__ void k_agg(const float* __restrict__ xw, const float* __restrict__ dinv,
                      const int* __restrict__ off, const int* __restrict__ srcs,
                      const float* __restrict__ b, float* __restrict__ h, int n) {
    int g = blockIdx.x * blockDim.x + threadIdx.x;
    int d = g >> 6, c = g & 63;
    if (d >= n) return;
    float dd = dinv[d];
    float acc = xw[(size_t)d * D_OUT + c] * dd * dd;  // self-loop message
    int k = off[d], kend = off[d + 1];
    for (; k < kend; ++k) {
        int s = srcs[k];
        float nrm = dd * dinv[s];
        acc += xw[(size_t)s * D_OUT + c] * nrm;
    }
    float v = acc + b[c];
    h[(size_t)d * D_OUT + c] = v > 0.f ? v : 0.f;
}

// 16 lanes per edge, float4 loads: out[e] = sigmoid(<h[i],h[j]>) + 1e-15
// fused: out[E+e] = (float)i, out[2E+e] = (float)j
__global__ void k_decode(const int* __restrict__ e0, const int* __restrict__ e1,
                         const float* __restrict__ h, float* __restrict__ out, int E) {
    int g = blockIdx.x * blockDim.x + threadIdx.x;
    int e = g >> 4, sub = g & 15;
    if (e >= E) return;
    int i = e0[e], j = e1[e];
    float4 a = *(const float4*)(h + (size_t)i * D_OUT + sub * 4);
    float4 bb = *(const float4*)(h + (size_t)j * D_OUT + sub * 4);
    float p = a.x * bb.x + a.y * bb.y + a.z * bb.z + a.w * bb.w;
#pragma unroll
    for (int o = 8; o >= 1; o >>= 1) p += __shfl_xor(p, o, 64);
    if (sub == 0) {
        out[e] = 1.0f / (1.0f + expf(-p)) + 1e-15f;
        out[E + e] = (float)i;
        out[2 * E + e] = (float)j;
    }
}

extern "C" void kernel_launch(void* const* d_in, const int* in_sizes, int n_in,
                              void* d_out, int out_size, void* d_ws, size_t ws_size,
                              hipStream_t stream) {
    const float* x = (const float*)d_in[0];
    const int*   ei = (const int*)d_in[1];
    const float* W = (const float*)d_in[2];
    const float* b = (const float*)d_in[3];

    const int N = in_sizes[0] / D_IN;
    const int E = in_sizes[1] / 2;
    const size_t NF = (size_t)N * D_OUT;

    float* out = (float*)d_out;  // [adj_pred (E), edge_index-as-float (2E)]

    float* ws   = (float*)d_ws;
    float* xw   = ws;                    // N*64 f32
    float* h    = ws + NF;               // N*64 f32
    float* dinv = ws + 2 * NF;           // N f32
    int*   cnt  = (int*)(ws + 2 * NF + N);  // N i32
    int*   off  = cnt + N;               // N+1 i32
    int*   srcs = off + N + 1;           // E i32

    const int* srcv = ei;      // edge_index[0] : message sources
    const int* dstv = ei + E;  // edge_index[1] : aggregation targets

    const int B = 256;
    const int gN  = (N + B - 1) / B;
    const int gNF = (int)((NF + B - 1) / B);
    const int gE  = (E + B - 1) / B;
    const int gD  = (int)(((long long)E * 16 + B - 1) / B);

    k_zero  <<<gN,  B, 0, stream>>>(cnt, N);
    k_xw    <<<gNF, B, 0, stream>>>(x, W, xw, N);
    k_deg   <<<gE,  B, 0, stream>>>(dstv, cnt, E);
    k_scan  <<<1, SCAN_T, 0, stream>>>(cnt, off, N);
    k_dinv  <<<gN,  B, 0, stream>>>(cnt, dinv, N);
    k_fill  <<<gE,  B, 0, stream>>>(srcv, dstv, off, cnt, srcs, E);
    k_agg   <<<gNF, B, 0, stream>>>(xw, dinv, off, srcs, b, h, N);
    k_decode<<<gD,  B, 0, stream>>>(srcv, dstv, h, out, E);
}

// Round 4
// 200.265 us; speedup vs baseline: 2.0421x; 1.6016x over previous
//
#include <hip/hip_runtime.h>
#include <hip/hip_bf16.h>

#define D_IN 32
#define D_OUT 64

// cnt[i] = 0
__global__ void k_zero(int* __restrict__ cnt, int n) {
    int i = blockIdx.x * blockDim.x + threadIdx.x;
    if (i < n) cnt[i] = 0;
}

// xw = x @ W   (x: [N,32], W: [32,64])
__global__ void k_xw(const float* __restrict__ x, const float* __restrict__ W,
                     float* __restrict__ xw, int n) {
    __shared__ float Ws[D_IN * D_OUT];
    for (int t = threadIdx.x; t < D_IN * D_OUT; t += blockDim.x) Ws[t] = W[t];
    __syncthreads();
    int g = blockIdx.x * blockDim.x + threadIdx.x;
    if (g >= n * D_OUT) return;
    int r = g >> 6, c = g & 63;
    const float* xr = x + (size_t)r * D_IN;
    float s = 0.f;
#pragma unroll
    for (int k = 0; k < D_IN; ++k) s += xr[k] * Ws[k * D_OUT + c];
    xw[g] = s;
}

// cnt[dst[e]] += 1
__global__ void k_deg(const int* __restrict__ dst, int* __restrict__ cnt, int E) {
    int e = blockIdx.x * blockDim.x + threadIdx.x;
    if (e < E) atomicAdd(&cnt[dst[e]], 1);
}

// ---- 3-phase exclusive scan of cnt[0..n) -> off[0..n] ----
// phase 1: per-256-block sums
__global__ void k_bsum(const int* __restrict__ cnt, int* __restrict__ bsum, int n) {
    __shared__ int sh[4];
    int t = threadIdx.x;
    int i = blockIdx.x * 256 + t;
    int v = (i < n) ? cnt[i] : 0;
#pragma unroll
    for (int o = 32; o >= 1; o >>= 1) v += __shfl_xor(v, o, 64);
    if ((t & 63) == 0) sh[t >> 6] = v;
    __syncthreads();
    if (t == 0) bsum[blockIdx.x] = sh[0] + sh[1] + sh[2] + sh[3];
}

// phase 2: single block exclusive-scans nb (<=256) block sums
__global__ void k_bscan(const int* __restrict__ bsum, int* __restrict__ boff, int nb) {
    __shared__ int sh[256];
    int t = threadIdx.x;
    int v = (t < nb) ? bsum[t] : 0;
    sh[t] = v;
    __syncthreads();
    for (int d = 1; d < 256; d <<= 1) {
        int u = (t >= d) ? sh[t - d] : 0;
        __syncthreads();
        sh[t] += u;
        __syncthreads();
    }
    if (t < nb) boff[t] = sh[t] - v;  // exclusive
}

// phase 3: per-block LDS scan, add block offset; also writes off[n]
__global__ void k_off(const int* __restrict__ cnt, const int* __restrict__ boff,
                      int* __restrict__ off, int n) {
    __shared__ int sh[256];
    int t = threadIdx.x;
    int i = blockIdx.x * 256 + t;
    int v = (i < n) ? cnt[i] : 0;
    sh[t] = v;
    __syncthreads();
    for (int d = 1; d < 256; d <<= 1) {
        int u = (t >= d) ? sh[t - d] : 0;
        __syncthreads();
        sh[t] += u;
        __syncthreads();
    }
    if (i <= n) off[i] = boff[blockIdx.x] + sh[t] - v;
}

// dinv[i] = rsqrt(cnt[i] + 1)   (self-loop included)
__global__ void k_dinv(const int* __restrict__ cnt, float* __restrict__ dinv, int n) {
    int i = blockIdx.x * blockDim.x + threadIdx.x;
    if (i < n) dinv[i] = rsqrtf((float)(cnt[i] + 1));
}

// bucket-fill: srcs[off[d] + slot] = src[e], consuming cnt as a down-counter
__global__ void k_fill(const int* __restrict__ src, const int* __restrict__ dst,
                       const int* __restrict__ off, int* __restrict__ cnt,
                       int* __restrict__ srcs, int E) {
    int e = blockIdx.x * blockDim.x + threadIdx.x;
    if (e >= E) return;
    int d = dst[e];
    int slot = atomicSub(&cnt[d], 1) - 1;  // unique in [0, deg)
    srcs[off[d] + slot] = src[e];
}

// one wave per node, 8-way ILP over edges:
// h[d] = relu( xw[d]*dd^2 + dd * sum_e xw[src]*dinv[src] + b )
__global__ void k_agg(const float* __restrict__ xw, const float* __restrict__ dinv,
                      const int* __restrict__ off, const int* __restrict__ srcs,
                      const float* __restrict__ b, float* __restrict__ h, int n) {
    int g = blockIdx.x * blockDim.x + threadIdx.x;
    int d = g >> 6, c = g & 63;
    if (d >= n) return;
    float dd = dinv[d];
    float self = xw[(size_t)d * D_OUT + c] * dd * dd;
    float a0 = 0.f, a1 = 0.f, a2 = 0.f, a3 = 0.f;
    int kend = off[d + 1];
    for (int k = off[d]; k < kend; k += 8) {
        int s[8];
        float v[8], w[8];
#pragma unroll
        for (int u = 0; u < 8; ++u) {
            int t = k + u;
            s[u] = srcs[t < kend ? t : kend - 1];  // clamped: loop runs only if kend>off[d]
        }
#pragma unroll
        for (int u = 0; u < 8; ++u) v[u] = xw[(size_t)s[u] * D_OUT + c];
#pragma unroll
        for (int u = 0; u < 8; ++u) w[u] = (k + u < kend) ? dinv[s[u]] : 0.f;
        a0 += v[0] * w[0]; a1 += v[1] * w[1]; a2 += v[2] * w[2]; a3 += v[3] * w[3];
        a0 += v[4] * w[4]; a1 += v[5] * w[5]; a2 += v[6] * w[6]; a3 += v[7] * w[7];
    }
    float r = self + dd * ((a0 + a1) + (a2 + a3)) + b[c];
    h[(size_t)d * D_OUT + c] = r > 0.f ? r : 0.f;
}

// 8 lanes per edge, 2x float4 per row: out[e] = sigmoid(<h[i],h[j]>) + 1e-15
// fused: out[E+e] = (float)i, out[2E+e] = (float)j
__global__ void k_decode(const int* __restrict__ e0, const int* __restrict__ e1,
                         const float* __restrict__ h, float* __restrict__ out, int E) {
    int g = blockIdx.x * blockDim.x + threadIdx.x;
    int e = g >> 3, sub = g & 7;
    if (e >= E) return;
    int i = e0[e], j = e1[e];
    const float4* hi = (const float4*)(h + (size_t)i * D_OUT + sub * 8);
    const float4* hj = (const float4*)(h + (size_t)j * D_OUT + sub * 8);
    float4 a0 = hi[0], a1 = hi[1];
    float4 b0 = hj[0], b1 = hj[1];
    float p = a0.x * b0.x + a0.y * b0.y + a0.z * b0.z + a0.w * b0.w
            + a1.x * b1.x + a1.y * b1.y + a1.z * b1.z + a1.w * b1.w;
    p += __shfl_xor(p, 1, 64);
    p += __shfl_xor(p, 2, 64);
    p += __shfl_xor(p, 4, 64);
    if (sub == 0) {
        out[e] = 1.0f / (1.0f + expf(-p)) + 1e-15f;
        out[E + e] = (float)i;
        out[2 * E + e] = (float)j;
    }
}

extern "C" void kernel_launch(void* const* d_in, const int* in_sizes, int n_in,
                              void* d_out, int out_size, void* d_ws, size_t ws_size,
                              hipStream_t stream) {
    const float* x = (const float*)d_in[0];
    const int*   ei = (const int*)d_in[1];
    const float* W = (const float*)d_in[2];
    const float* b = (const float*)d_in[3];

    const int N = in_sizes[0] / D_IN;
    const int E = in_sizes[1] / 2;
    const size_t NF = (size_t)N * D_OUT;

    float* out = (float*)d_out;  // [adj_pred (E), edge_index-as-float (2E)]

    float* ws   = (float*)d_ws;
    float* xw   = ws;                        // N*64 f32
    float* h    = ws + NF;                   // N*64 f32
    float* dinv = ws + 2 * NF;               // N f32
    int*   cnt  = (int*)(ws + 2 * NF + N);   // N i32
    int*   off  = cnt + N;                   // N+1 i32
    int*   srcs = off + N + 1;               // E i32
    int*   bsum = srcs + E;                  // nb i32
    int*   boff = bsum + 256;                // nb i32

    const int* srcv = ei;      // edge_index[0] : message sources
    const int* dstv = ei + E;  // edge_index[1] : aggregation targets

    const int B = 256;
    const int gN  = (N + B - 1) / B;
    const int gNF = (int)((NF + B - 1) / B);
    const int gE  = (E + B - 1) / B;
    const int nb  = (N + 1 + 255) / 256;     // covers index n for off[n]
    const int gD  = (int)(((long long)E * 8 + B - 1) / B);

    k_zero  <<<gN,  B, 0, stream>>>(cnt, N);
    k_xw    <<<gNF, B, 0, stream>>>(x, W, xw, N);
    k_deg   <<<gE,  B, 0, stream>>>(dstv, cnt, E);
    k_bsum  <<<nb,  B, 0, stream>>>(cnt, bsum, N);
    k_bscan <<<1,   B, 0, stream>>>(bsum, boff, nb);
    k_off   <<<nb,  B, 0, stream>>>(cnt, boff, off, N);
    k_dinv  <<<gN,  B, 0, stream>>>(cnt, dinv, N);
    k_fill  <<<gE,  B, 0, stream>>>(srcv, dstv, off, cnt, srcs, E);
    k_agg   <<<gNF, B, 0, stream>>>(xw, dinv, off, srcs, b, h, N);
    k_decode<<<gD,  B, 0, stream>>>(srcv, dstv, h, out, E);
}

// Round 5
// 167.837 us; speedup vs baseline: 2.4366x; 1.1932x over previous
//
#include <hip/hip_runtime.h>
#include <hip/hip_bf16.h>

#define D_IN 32
#define D_OUT 64

typedef unsigned short ushort8 __attribute__((ext_vector_type(8)));

__device__ __forceinline__ float bf2f(unsigned short u) {
    return __uint_as_float(((unsigned int)u) << 16);
}
__device__ __forceinline__ unsigned short f2bf(float f) {
    unsigned int x = __float_as_uint(f);
    x += 0x7fff + ((x >> 16) & 1);  // RNE
    return (unsigned short)(x >> 16);
}

// xw = x @ W  (f32), fused: cnt[i] = 0
__global__ void k_xw_zero(const float* __restrict__ x, const float* __restrict__ W,
                          float* __restrict__ xw, int* __restrict__ cnt, int n) {
    __shared__ float Ws[D_IN * D_OUT];
    for (int t = threadIdx.x; t < D_IN * D_OUT; t += blockDim.x) Ws[t] = W[t];
    __syncthreads();
    int g = blockIdx.x * blockDim.x + threadIdx.x;
    if (g < n) cnt[g] = 0;
    if (g >= n * D_OUT) return;
    int r = g >> 6, c = g & 63;
    const float* xr = x + (size_t)r * D_IN;
    float s = 0.f;
#pragma unroll
    for (int k = 0; k < D_IN; ++k) s += xr[k] * Ws[k * D_OUT + c];
    xw[g] = s;
}

// cnt[dst[e]] += 1, 4 edges/thread via int4
__global__ void k_deg4(const int* __restrict__ dst, int* __restrict__ cnt, int E) {
    int t = blockIdx.x * blockDim.x + threadIdx.x;
    int e0 = t * 4;
    if (e0 + 3 < E) {
        int4 d4 = *(const int4*)(dst + e0);
        atomicAdd(&cnt[d4.x], 1);
        atomicAdd(&cnt[d4.y], 1);
        atomicAdd(&cnt[d4.z], 1);
        atomicAdd(&cnt[d4.w], 1);
    } else {
        for (int e = e0; e < E; ++e) atomicAdd(&cnt[dst[e]], 1);
    }
}

// ---- 3-phase exclusive scan of cnt[0..n) -> off[0..n] ----
__global__ void k_bsum(const int* __restrict__ cnt, int* __restrict__ bsum, int n) {
    __shared__ int sh[4];
    int t = threadIdx.x;
    int i = blockIdx.x * 256 + t;
    int v = (i < n) ? cnt[i] : 0;
#pragma unroll
    for (int o = 32; o >= 1; o >>= 1) v += __shfl_xor(v, o, 64);
    if ((t & 63) == 0) sh[t >> 6] = v;
    __syncthreads();
    if (t == 0) bsum[blockIdx.x] = sh[0] + sh[1] + sh[2] + sh[3];
}

__global__ void k_bscan(const int* __restrict__ bsum, int* __restrict__ boff, int nb) {
    __shared__ int sh[256];
    int t = threadIdx.x;
    int v = (t < nb) ? bsum[t] : 0;
    sh[t] = v;
    __syncthreads();
    for (int d = 1; d < 256; d <<= 1) {
        int u = (t >= d) ? sh[t - d] : 0;
        __syncthreads();
        sh[t] += u;
        __syncthreads();
    }
    if (t < nb) boff[t] = sh[t] - v;  // exclusive
}

// per-block scan + block offset; fused: dinv[i] = rsqrt(cnt[i]+1)
__global__ void k_off_dinv(const int* __restrict__ cnt, const int* __restrict__ boff,
                           int* __restrict__ off, float* __restrict__ dinv, int n) {
    __shared__ int sh[256];
    int t = threadIdx.x;
    int i = blockIdx.x * 256 + t;
    int v = (i < n) ? cnt[i] : 0;
    sh[t] = v;
    __syncthreads();
    for (int d = 1; d < 256; d <<= 1) {
        int u = (t >= d) ? sh[t - d] : 0;
        __syncthreads();
        sh[t] += u;
        __syncthreads();
    }
    if (i <= n) off[i] = boff[blockIdx.x] + sh[t] - v;
    if (i < n) dinv[i] = rsqrtf((float)(cnt[i] + 1));
}

// xws[i][c] = bf16( xw[i][c] * dinv[i] )
__global__ void k_prep(const float* __restrict__ xw, const float* __restrict__ dinv,
                       unsigned short* __restrict__ xws, int n) {
    int g = blockIdx.x * blockDim.x + threadIdx.x;
    if (g >= n * D_OUT) return;
    int r = g >> 6;
    xws[g] = f2bf(xw[g] * dinv[r]);
}

// bucket-fill srcs (counting-sort placement), 4 edges/thread
__global__ void k_fill4(const int* __restrict__ src, const int* __restrict__ dst,
                        const int* __restrict__ off, int* __restrict__ cnt,
                        int* __restrict__ srcs, int E) {
    int t = blockIdx.x * blockDim.x + threadIdx.x;
    int e0 = t * 4;
    if (e0 + 3 < E) {
        int4 s4 = *(const int4*)(src + e0);
        int4 d4 = *(const int4*)(dst + e0);
        int d, slot;
        d = d4.x; slot = atomicSub(&cnt[d], 1) - 1; srcs[off[d] + slot] = s4.x;
        d = d4.y; slot = atomicSub(&cnt[d], 1) - 1; srcs[off[d] + slot] = s4.y;
        d = d4.z; slot = atomicSub(&cnt[d], 1) - 1; srcs[off[d] + slot] = s4.z;
        d = d4.w; slot = atomicSub(&cnt[d], 1) - 1; srcs[off[d] + slot] = s4.w;
    } else {
        for (int e = e0; e < E; ++e) {
            int d = dst[e];
            int slot = atomicSub(&cnt[d], 1) - 1;
            srcs[off[d] + slot] = src[e];
        }
    }
}

// one wave per node, 8-way ILP: h[d] = bf16(relu( dd*(xws[d] + sum_s xws[s]) + b ))
__global__ void k_agg(const unsigned short* __restrict__ xws, const float* __restrict__ dinv,
                      const int* __restrict__ off, const int* __restrict__ srcs,
                      const float* __restrict__ b, unsigned short* __restrict__ h, int n) {
    int g = blockIdx.x * blockDim.x + threadIdx.x;
    int d = g >> 6, c = g & 63;
    if (d >= n) return;
    float dd = dinv[d];
    float a0 = bf2f(xws[(size_t)d * D_OUT + c]);  // self term (xw[d]*dd)
    float a1 = 0.f, a2 = 0.f, a3 = 0.f;
    int kend = off[d + 1];
    for (int k = off[d]; k < kend; k += 8) {
        int s[8];
        float v[8];
#pragma unroll
        for (int u = 0; u < 8; ++u) {
            int t = k + u;
            s[u] = srcs[t < kend ? t : kend - 1];
        }
#pragma unroll
        for (int u = 0; u < 8; ++u) {
            float x = bf2f(xws[(size_t)s[u] * D_OUT + c]);
            v[u] = (k + u < kend) ? x : 0.f;
        }
        a0 += v[0]; a1 += v[1]; a2 += v[2]; a3 += v[3];
        a0 += v[4]; a1 += v[5]; a2 += v[6]; a3 += v[7];
    }
    float r = dd * ((a0 + a1) + (a2 + a3)) + b[c];
    h[(size_t)d * D_OUT + c] = f2bf(r > 0.f ? r : 0.f);
}

// 4 lanes/edge, 2x ushort8 per row: out[e] = sigmoid(<h[i],h[j]>) + 1e-15
// fused: out[E+e] = (float)i, out[2E+e] = (float)j
__global__ void k_decode(const int* __restrict__ e0, const int* __restrict__ e1,
                         const unsigned short* __restrict__ h, float* __restrict__ out, int E) {
    int g = blockIdx.x * blockDim.x + threadIdx.x;
    int e = g >> 2, q = g & 3;
    if (e >= E) return;
    int i = e0[e], j = e1[e];
    const ushort8* hi = (const ushort8*)(h + (size_t)i * D_OUT + q * 16);
    const ushort8* hj = (const ushort8*)(h + (size_t)j * D_OUT + q * 16);
    ushort8 ai0 = hi[0], ai1 = hi[1];
    ushort8 bj0 = hj[0], bj1 = hj[1];
    float p = 0.f;
#pragma unroll
    for (int t = 0; t < 8; ++t)
        p += bf2f(ai0[t]) * bf2f(bj0[t]) + bf2f(ai1[t]) * bf2f(bj1[t]);
    p += __shfl_xor(p, 1, 64);
    p += __shfl_xor(p, 2, 64);
    if (q == 0) {
        out[e] = 1.0f / (1.0f + expf(-p)) + 1e-15f;
        out[E + e] = (float)i;
        out[2 * E + e] = (float)j;
    }
}

extern "C" void kernel_launch(void* const* d_in, const int* in_sizes, int n_in,
                              void* d_out, int out_size, void* d_ws, size_t ws_size,
                              hipStream_t stream) {
    const float* x = (const float*)d_in[0];
    const int*   ei = (const int*)d_in[1];
    const float* W = (const float*)d_in[2];
    const float* b = (const float*)d_in[3];

    const int N = in_sizes[0] / D_IN;
    const int E = in_sizes[1] / 2;
    const size_t NF = (size_t)N * D_OUT;

    float* out = (float*)d_out;  // [adj_pred (E), edge_index-as-float (2E)]

    char* base = (char*)d_ws;
    float*          xw   = (float*)base;                    // NF f32
    unsigned short* xws  = (unsigned short*)(base + NF * 4);  // NF bf16
    unsigned short* h    = (unsigned short*)(base + NF * 6);  // NF bf16
    float*          dinv = (float*)(base + NF * 8);          // N f32
    int*            cnt  = (int*)(base + NF * 8 + (size_t)N * 4);  // N
    int*            off  = cnt + N;                          // N+1
    int*            srcs = off + N + 1;                      // E
    int*            bsum = srcs + E;                         // 256
    int*            boff = bsum + 256;                       // 256

    const int* srcv = ei;      // edge_index[0] : message sources
    const int* dstv = ei + E;  // edge_index[1] : aggregation targets

    const int B = 256;
    const int gNF = (int)((NF + B - 1) / B);
    const int gE4 = (E / 4 + B - 1) / B + 1;
    const int nb  = (N + 1 + 255) / 256;
    const int gD  = (int)(((long long)E * 4 + B - 1) / B);

    k_xw_zero <<<gNF, B, 0, stream>>>(x, W, xw, cnt, N);
    k_deg4    <<<gE4, B, 0, stream>>>(dstv, cnt, E);
    k_bsum    <<<nb,  B, 0, stream>>>(cnt, bsum, N);
    k_bscan   <<<1,   B, 0, stream>>>(bsum, boff, nb);
    k_off_dinv<<<nb,  B, 0, stream>>>(cnt, boff, off, dinv, N);
    k_prep    <<<gNF, B, 0, stream>>>(xw, dinv, xws, N);
    k_fill4   <<<gE4, B, 0, stream>>>(srcv, dstv, off, cnt, srcs, E);
    k_agg     <<<gNF, B, 0, stream>>>(xws, dinv, off, srcs, b, h, N);
    k_decode  <<<gD,  B, 0, stream>>>(srcv, dstv, h, out, E);
}